// Round 8
// baseline (1072.022 us; speedup 1.0000x reference)
//
#include <hip/hip_runtime.h>
#include <math.h>

// Shapes (B=1 throughout)
#define S_LEN 2048
#define D_MODEL 4096
#define NH 16
#define TOPK_ 1024

typedef float f32x4 __attribute__((ext_vector_type(4)));
typedef short bf16x8 __attribute__((ext_vector_type(8)));

__device__ __forceinline__ unsigned short f2bf(float f) {
  unsigned u = __float_as_uint(f);
  u += 0x7fffu + ((u >> 16) & 1u);  // RNE
  return (unsigned short)(u >> 16);
}

// async global->LDS, 16B per lane. LDS dest = wave-uniform base + lane*16 (m97 pattern).
__device__ __forceinline__ void gload16(const unsigned short* g, unsigned short* l) {
  __builtin_amdgcn_global_load_lds(
      (const __attribute__((address_space(1))) unsigned int*)g,
      (__attribute__((address_space(3))) unsigned int*)l, 16, 0, 0);
}

// ---------------- bf16 MFMA GEMM, bf16 output with scale ----------------
// Tile 128x128, BK=32, 256 threads. Double-buffered global_load_lds staging.
__global__ __launch_bounds__(256) void gemm_bf16x_bf(const unsigned short* __restrict__ A,
                                                     const unsigned short* __restrict__ Bt,
                                                     unsigned short* __restrict__ C,
                                                     int K, int lda, int ldb, int ldc,
                                                     int za, int zb, int zc, float scale) {
  A += (size_t)blockIdx.z * za;
  Bt += (size_t)blockIdx.z * zb;
  C += (size_t)blockIdx.z * zc;
  __shared__ __align__(16) unsigned short As[2][128 * 32];
  __shared__ __align__(16) unsigned short Bs[2][128 * 32];
  const int t = threadIdx.x, lane = t & 63, w = t >> 6;
  const int m0 = blockIdx.y * 128, n0 = blockIdx.x * 128;
  const int mb = (w & 1) * 64, nb = (w >> 1) * 64;
  const int fr = lane & 15, fq = lane >> 4;
  f32x4 acc[4][4];
#pragma unroll
  for (int i = 0; i < 4; i++)
#pragma unroll
    for (int j = 0; j < 4; j++) acc[i][j] = (f32x4){0.f, 0.f, 0.f, 0.f};
  const int grow = t >> 2, gsub = (t & 3) * 8;
  const int wb = w * 512;
  const unsigned short* AgL = A + (size_t)(m0 + grow) * lda + gsub;
  const unsigned short* AgH = A + (size_t)(m0 + 64 + grow) * lda + gsub;
  const unsigned short* BgL = Bt + (size_t)(n0 + grow) * ldb + gsub;
  const unsigned short* BgH = Bt + (size_t)(n0 + 64 + grow) * ldb + gsub;
  gload16(AgL, &As[0][wb]);
  gload16(AgH, &As[0][2048 + wb]);
  gload16(BgL, &Bs[0][wb]);
  gload16(BgH, &Bs[0][2048 + wb]);
  int cur = 0;
  for (int k0 = 0; k0 < K; k0 += 32) {
    __syncthreads();
    if (k0 + 32 < K) {
      gload16(AgL + k0 + 32, &As[cur ^ 1][wb]);
      gload16(AgH + k0 + 32, &As[cur ^ 1][2048 + wb]);
      gload16(BgL + k0 + 32, &Bs[cur ^ 1][wb]);
      gload16(BgH + k0 + 32, &Bs[cur ^ 1][2048 + wb]);
    }
    bf16x8 af[4], bfr[4];
#pragma unroll
    for (int mt = 0; mt < 4; mt++) af[mt] = *(const bf16x8*)&As[cur][(mb + mt * 16 + fr) * 32 + fq * 8];
#pragma unroll
    for (int nt = 0; nt < 4; nt++) bfr[nt] = *(const bf16x8*)&Bs[cur][(nb + nt * 16 + fr) * 32 + fq * 8];
#pragma unroll
    for (int mt = 0; mt < 4; mt++)
#pragma unroll
      for (int nt = 0; nt < 4; nt++)
        acc[mt][nt] = __builtin_amdgcn_mfma_f32_16x16x32_bf16(af[mt], bfr[nt], acc[mt][nt], 0, 0, 0);
    cur ^= 1;
  }
#pragma unroll
  for (int mt = 0; mt < 4; mt++) {
#pragma unroll
    for (int r = 0; r < 4; r++) {
      int row = m0 + mb + mt * 16 + fq * 4 + r;
      unsigned short* cp = C + (size_t)row * ldc + n0 + nb + fr;
#pragma unroll
      for (int nt = 0; nt < 4; nt++) cp[nt * 16] = f2bf(acc[mt][nt][r] * scale);
    }
  }
}

// split-K: blockIdx.z = K-chunk; partials atomicAdd'ed into PRE-ZEROED fp32 C.
// Validated R7 (cq/ki/kvp): raises block count for occupancy-starved shapes.
__global__ __launch_bounds__(256) void gemm_bf16x_sk(const unsigned short* __restrict__ A,
                                                     const unsigned short* __restrict__ Bt,
                                                     float* __restrict__ C,
                                                     int Kc, int lda, int ldb, int ldc) {
  const int kbase = blockIdx.z * Kc;
  __shared__ __align__(16) unsigned short As[2][128 * 32];
  __shared__ __align__(16) unsigned short Bs[2][128 * 32];
  const int t = threadIdx.x, lane = t & 63, w = t >> 6;
  const int m0 = blockIdx.y * 128, n0 = blockIdx.x * 128;
  const int mb = (w & 1) * 64, nb = (w >> 1) * 64;
  const int fr = lane & 15, fq = lane >> 4;
  f32x4 acc[4][4];
#pragma unroll
  for (int i = 0; i < 4; i++)
#pragma unroll
    for (int j = 0; j < 4; j++) acc[i][j] = (f32x4){0.f, 0.f, 0.f, 0.f};
  const int grow = t >> 2, gsub = (t & 3) * 8;
  const int wb = w * 512;
  const unsigned short* AgL = A + (size_t)(m0 + grow) * lda + kbase + gsub;
  const unsigned short* AgH = A + (size_t)(m0 + 64 + grow) * lda + kbase + gsub;
  const unsigned short* BgL = Bt + (size_t)(n0 + grow) * ldb + kbase + gsub;
  const unsigned short* BgH = Bt + (size_t)(n0 + 64 + grow) * ldb + kbase + gsub;
  gload16(AgL, &As[0][wb]);
  gload16(AgH, &As[0][2048 + wb]);
  gload16(BgL, &Bs[0][wb]);
  gload16(BgH, &Bs[0][2048 + wb]);
  int cur = 0;
  for (int k0 = 0; k0 < Kc; k0 += 32) {
    __syncthreads();
    if (k0 + 32 < Kc) {
      gload16(AgL + k0 + 32, &As[cur ^ 1][wb]);
      gload16(AgH + k0 + 32, &As[cur ^ 1][2048 + wb]);
      gload16(BgL + k0 + 32, &Bs[cur ^ 1][wb]);
      gload16(BgH + k0 + 32, &Bs[cur ^ 1][2048 + wb]);
    }
    bf16x8 af[4], bfr[4];
#pragma unroll
    for (int mt = 0; mt < 4; mt++) af[mt] = *(const bf16x8*)&As[cur][(mb + mt * 16 + fr) * 32 + fq * 8];
#pragma unroll
    for (int nt = 0; nt < 4; nt++) bfr[nt] = *(const bf16x8*)&Bs[cur][(nb + nt * 16 + fr) * 32 + fq * 8];
#pragma unroll
    for (int mt = 0; mt < 4; mt++)
#pragma unroll
      for (int nt = 0; nt < 4; nt++)
        acc[mt][nt] = __builtin_amdgcn_mfma_f32_16x16x32_bf16(af[mt], bfr[nt], acc[mt][nt], 0, 0, 0);
    cur ^= 1;
  }
#pragma unroll
  for (int mt = 0; mt < 4; mt++) {
#pragma unroll
    for (int r = 0; r < 4; r++) {
      int row = m0 + mb + mt * 16 + fq * 4 + r;
      float* cp = C + (size_t)row * ldc + n0 + nb + fr;
#pragma unroll
      for (int nt = 0; nt < 4; nt++) atomicAdd(cp + nt * 16, acc[mt][nt][r]);
    }
  }
}

// ---------------- cast fp32 -> bf16 (8 elems/thread) ----------------
__global__ __launch_bounds__(256) void cast_bf16(const float* __restrict__ in,
                                                 unsigned short* __restrict__ out) {
  size_t i = (size_t)(blockIdx.x * 256 + threadIdx.x) * 8;
  float4 v0 = *(const float4*)(in + i);
  float4 v1 = *(const float4*)(in + i + 4);
  unsigned short tmp[8] = {f2bf(v0.x), f2bf(v0.y), f2bf(v0.z), f2bf(v0.w),
                           f2bf(v1.x), f2bf(v1.y), f2bf(v1.z), f2bf(v1.w)};
  *(float4*)(out + i) = *(float4*)tmp;
}

// ---------------- transpose+cast: in fp32 [K,N] -> out bf16 [Npad,K] ----------------
__global__ __launch_bounds__(256) void transpose_cast(const float* __restrict__ in,
                                                      unsigned short* __restrict__ out,
                                                      int K, int N) {
  __shared__ float buf[64][33];
  const int k0 = blockIdx.y * 64, n0 = blockIdx.x * 32;
  const int t = threadIdx.x;
  const bool valid = (n0 < N);
  if (valid) {
#pragma unroll
    for (int i = 0; i < 2; i++) {
      int c = i * 256 + t;
      int kk = c >> 3, nn = (c & 7) * 4;
      float4 v = *(const float4*)(in + (size_t)(k0 + kk) * N + n0 + nn);
      buf[kk][nn] = v.x; buf[kk][nn + 1] = v.y; buf[kk][nn + 2] = v.z; buf[kk][nn + 3] = v.w;
    }
  }
  __syncthreads();
  const int n = t >> 3, k8 = (t & 7) * 8;
  unsigned short tmp[8];
#pragma unroll
  for (int j = 0; j < 8; j++) tmp[j] = valid ? f2bf(buf[k8 + j][n]) : (unsigned short)0;
  *(float4*)(out + (size_t)(n0 + n) * K + k0 + k8) = *(float4*)tmp;
}

// ---------------- transpose w_v slice: wvT[h][d][c] = wkvbbf[c][h*256+128+d] ----------------
__global__ __launch_bounds__(256) void transpose_wv(const unsigned short* __restrict__ wkvbbf,
                                                    unsigned short* __restrict__ wvT) {
  __shared__ unsigned short tile[128][136];
  const int c0 = blockIdx.x * 128, h = blockIdx.y;
  const int t = threadIdx.x;
  for (int i = t; i < 128 * 16; i += 256) {
    int c = i >> 4, sub = (i & 15) * 8;
    *(float4*)&tile[c][sub] = *(const float4*)(wkvbbf + (size_t)(c0 + c) * 4096 + h * 256 + 128 + sub);
  }
  __syncthreads();
  for (int i = t; i < 128 * 16; i += 256) {
    int d = i >> 4, cs = (i & 15) * 8;
    unsigned short tmp[8];
#pragma unroll
    for (int j = 0; j < 8; j++) tmp[j] = tile[cs + j][d];
    *(float4*)(wvT + (size_t)h * 65536 + (size_t)d * 512 + c0 + cs) = *(float4*)tmp;
  }
}

// ---------------- RMSNorm in place ----------------
__global__ __launch_bounds__(256) void rmsnorm_kernel(float* __restrict__ x,
                                                      const float* __restrict__ w,
                                                      int ncol, int stride) {
  const int s = blockIdx.x, t = threadIdx.x;
  float* row = x + (size_t)s * stride;
  float ss = 0.f;
  for (int d = t; d < ncol; d += 256) { float v = row[d]; ss += v * v; }
  __shared__ float red[256];
  red[t] = ss;
  __syncthreads();
  for (int o = 128; o > 0; o >>= 1) { if (t < o) red[t] += red[t + o]; __syncthreads(); }
  float r = 1.0f / sqrtf(red[0] / (float)ncol + 1e-6f);
  for (int d = t; d < ncol; d += 256) row[d] = row[d] * r * w[d];
}

// RMSNorm in place + bf16 copy out
__global__ __launch_bounds__(256) void rmsnorm_bf16_kernel(float* __restrict__ x,
                                                           const float* __restrict__ w,
                                                           unsigned short* __restrict__ xbf,
                                                           int ncol, int stride) {
  const int s = blockIdx.x, t = threadIdx.x;
  float* row = x + (size_t)s * stride;
  float ss = 0.f;
  for (int d = t; d < ncol; d += 256) { float v = row[d]; ss += v * v; }
  __shared__ float red[256];
  red[t] = ss;
  __syncthreads();
  for (int o = 128; o > 0; o >>= 1) { if (t < o) red[t] += red[t + o]; __syncthreads(); }
  float r = 1.0f / sqrtf(red[0] / (float)ncol + 1e-6f);
  for (int d = t; d < ncol; d += 256) {
    float v = row[d] * r * w[d];
    row[d] = v;
    xbf[(size_t)s * ncol + d] = f2bf(v);
  }
}

// ---------------- LayerNorm in place over 128 cols ----------------
__global__ __launch_bounds__(128) void layernorm128_kernel(float* __restrict__ x,
                                                           const float* __restrict__ w,
                                                           const float* __restrict__ b) {
  const int s = blockIdx.x, t = threadIdx.x;
  float* row = x + (size_t)s * 128;
  __shared__ float red[128];
  float v = row[t];
  red[t] = v;
  __syncthreads();
  for (int o = 64; o > 0; o >>= 1) { if (t < o) red[t] += red[t + o]; __syncthreads(); }
  float mu = red[0] / 128.f;
  __syncthreads();
  float d = v - mu;
  red[t] = d * d;
  __syncthreads();
  for (int o = 64; o > 0; o >>= 1) { if (t < o) red[t] += red[t + o]; __syncthreads(); }
  float var = red[0] / 128.f;
  row[t] = d * (1.0f / sqrtf(var + 1e-5f)) * w[t] + b[t];
}

// ---------------- RoPE kernels ----------------
__global__ __launch_bounds__(256) void rope_q_inter(float* __restrict__ q,
                                                    const float* __restrict__ cosp,
                                                    const float* __restrict__ sinp) {
  int id = blockIdx.x * 256 + threadIdx.x;
  int s = id >> 9, r = id & 511, h = r >> 5, j = r & 31;
  float c = cosp[s * 32 + j], sn = sinp[s * 32 + j];
  float* base = q + (size_t)s * (NH * 192) + h * 192 + 128 + 2 * j;
  float x0 = base[0], x1 = base[1];
  base[0] = x0 * c - x1 * sn;
  base[1] = x0 * sn + x1 * c;
}

__global__ __launch_bounds__(256) void rope_k_inter(float* __restrict__ kv,
                                                    const float* __restrict__ cosp,
                                                    const float* __restrict__ sinp,
                                                    int stride) {
  int id = blockIdx.x * 256 + threadIdx.x;
  int s = id >> 5, j = id & 31;
  float c = cosp[s * 32 + j], sn = sinp[s * 32 + j];
  float* base = kv + (size_t)s * stride + 512 + 2 * j;
  float x0 = base[0], x1 = base[1];
  base[0] = x0 * c - x1 * sn;
  base[1] = x0 * sn + x1 * c;
}

__global__ __launch_bounds__(256) void rope_qi_nonint(float* __restrict__ qi,
                                                      const float* __restrict__ cosp,
                                                      const float* __restrict__ sinp) {
  int id = blockIdx.x * 256 + threadIdx.x;
  int s = id >> 9, r = id & 511, n = r >> 5, j = r & 31;
  float c = cosp[s * 32 + j], sn = sinp[s * 32 + j];
  float* base = qi + (size_t)s * 2048 + n * 128;
  float xr = base[j], xi = base[j + 32];
  base[j] = xr * c - xi * sn;
  base[j + 32] = xr * sn + xi * c;
}

__global__ __launch_bounds__(256) void rope_ki_nonint(float* __restrict__ ki,
                                                      const float* __restrict__ cosp,
                                                      const float* __restrict__ sinp) {
  int id = blockIdx.x * 256 + threadIdx.x;
  int s = id >> 5, j = id & 31;
  float c = cosp[s * 32 + j], sn = sinp[s * 32 + j];
  float* base = ki + (size_t)s * 128;
  float xr = base[j], xi = base[j + 32];
  base[j] = xr * c - xi * sn;
  base[j + 32] = xr * sn + xi * c;
}

// ---------------- wts = hidden @ idx_w_proj * (0.25 * 128^-0.5)  (iscale folded) ----------------
__global__ __launch_bounds__(256) void wts_kernel(const float* __restrict__ hs,
                                                  const float* __restrict__ wp,
                                                  float* __restrict__ wts) {
  const int s = blockIdx.x, t = threadIdx.x;
  float acc[16] = {};
  for (int d = t; d < D_MODEL; d += 256) {
    float h = hs[(size_t)s * D_MODEL + d];
    const float* w = wp + (size_t)d * 16;
#pragma unroll
    for (int n = 0; n < 16; n++) acc[n] += h * w[n];
  }
  __shared__ float red[16][256];
#pragma unroll
  for (int n = 0; n < 16; n++) red[n][t] = acc[n];
  __syncthreads();
  for (int o = 128; o > 0; o >>= 1) {
    if (t < o) {
#pragma unroll
      for (int n = 0; n < 16; n++) red[n][t] += red[n][t + o];
    }
    __syncthreads();
  }
  if (t < 16) wts[(size_t)s * 16 + t] = red[t][0] * 0.022097086912079613f;
}

// ---------------- indexer scores via MFMA, 64x64 lower-tri tiles ----------------
__global__ __launch_bounds__(256) void indexer_mfma(const unsigned short* __restrict__ qibf,
                                                    const unsigned short* __restrict__ kibf,
                                                    const float* __restrict__ wts,
                                                    float* __restrict__ isc) {
  __shared__ unsigned short kis[64 * 136];
  __shared__ unsigned short qis[64 * 136];
  __shared__ float wt_s[64 * 16];
  const int t = threadIdx.x, lane = t & 63, w = t >> 6;
  const int ln = lane & 15, quad = lane >> 4;
  int b = blockIdx.x;
  int qt = (int)((sqrtf(8.0f * b + 1.0f) - 1.0f) * 0.5f);
  while ((qt + 1) * (qt + 2) / 2 <= b) qt++;
  while (qt * (qt + 1) / 2 > b) qt--;
  const int kt = b - qt * (qt + 1) / 2;
  const int q0 = qt * 64, k0 = kt * 64;
#pragma unroll
  for (int p = 0; p < 4; p++) {
    int i = t + p * 256;
    int row = i >> 4, sub = (i & 15) * 8;
    *(float4*)&kis[row * 136 + sub] = *(const float4*)(kibf + (size_t)(k0 + row) * 128 + sub);
  }
  {
    int rw = t >> 2, n4 = (t & 3) * 4;
    *(float4*)&wt_s[rw * 16 + n4] = *(const float4*)(wts + (size_t)(q0 + rw) * 16 + n4);
  }
  __syncthreads();
  bf16x8 kb[4][4];
#pragma unroll
  for (int nt = 0; nt < 4; nt++)
#pragma unroll
    for (int kk = 0; kk < 4; kk++)
      kb[nt][kk] = *(const bf16x8*)&kis[(nt * 16 + ln) * 136 + kk * 32 + quad * 8];
  f32x4 iacc[4];
#pragma unroll
  for (int nt = 0; nt < 4; nt++) iacc[nt] = (f32x4){0.f, 0.f, 0.f, 0.f};

  for (int n = 0; n < 16; n++) {
    __syncthreads();
#pragma unroll
    for (int p = 0; p < 4; p++) {
      int i = t + p * 256;
      int row = i >> 4, sub = (i & 15) * 8;
      *(float4*)&qis[row * 136 + sub] =
          *(const float4*)(qibf + (size_t)(q0 + row) * 2048 + n * 128 + sub);
    }
    __syncthreads();
    bf16x8 qa[4];
#pragma unroll
    for (int kk = 0; kk < 4; kk++)
      qa[kk] = *(const bf16x8*)&qis[(w * 16 + ln) * 136 + kk * 32 + quad * 8];
    float wv0 = wt_s[(w * 16 + quad * 4 + 0) * 16 + n];
    float wv1 = wt_s[(w * 16 + quad * 4 + 1) * 16 + n];
    float wv2 = wt_s[(w * 16 + quad * 4 + 2) * 16 + n];
    float wv3 = wt_s[(w * 16 + quad * 4 + 3) * 16 + n];
#pragma unroll
    for (int nt = 0; nt < 4; nt++) {
      f32x4 sacc = (f32x4){0.f, 0.f, 0.f, 0.f};
#pragma unroll
      for (int kk = 0; kk < 4; kk++)
        sacc = __builtin_amdgcn_mfma_f32_16x16x32_bf16(qa[kk], kb[nt][kk], sacc, 0, 0, 0);
      iacc[nt][0] += fmaxf(sacc[0], 0.f) * wv0;
      iacc[nt][1] += fmaxf(sacc[1], 0.f) * wv1;
      iacc[nt][2] += fmaxf(sacc[2], 0.f) * wv2;
      iacc[nt][3] += fmaxf(sacc[3], 0.f) * wv3;
    }
  }
#pragma unroll
  for (int nt = 0; nt < 4; nt++) {
#pragma unroll
    for (int r = 0; r < 4; r++) {
      int qg = q0 + w * 16 + quad * 4 + r;
      int kg = k0 + nt * 16 + ln;
      isc[(size_t)qg * 2048 + kg] = (kg <= qg) ? iacc[nt][r] : -1.0e30f;
    }
  }
}

// ---------------- exact top-1024 per row (jax tie semantics) ----------------
__global__ __launch_bounds__(256) void topk_select(const float* __restrict__ sc,
                                                   int* __restrict__ sel,
                                                   int* __restrict__ selcnt) {
  const int s = blockIdx.x, t = threadIdx.x;
  if (s < TOPK_) {
    for (int k = t; k <= s; k += 256) sel[(size_t)s * TOPK_ + k] = k;
    if (t == 0) selcnt[s] = s + 1;
    return;
  }
  __shared__ unsigned keys[2048];
  __shared__ unsigned hist[256];
  __shared__ unsigned sh_prefix, sh_K, sh_cnt;
  const int L = s + 1;
  for (int k = t; k < L; k += 256) {
    unsigned u = __float_as_uint(sc[(size_t)s * 2048 + k]);
    u = (u & 0x80000000u) ? ~u : (u | 0x80000000u);
    keys[k] = u;
  }
  if (t == 0) { sh_prefix = 0u; sh_K = TOPK_; sh_cnt = 0u; }
  __syncthreads();
#pragma unroll
  for (int pass = 0; pass < 4; pass++) {
    const int shift = 24 - 8 * pass;
    const unsigned mask_hi = (pass == 0) ? 0u : (0xFFFFFFFFu << (shift + 8));
    hist[t] = 0u;
    __syncthreads();
    unsigned prefix = sh_prefix;
    for (int k = t; k < L; k += 256) {
      unsigned u = keys[k];
      if ((u & mask_hi) == prefix) atomicAdd(&hist[(u >> shift) & 255u], 1u);
    }
    __syncthreads();
    if (t == 0) {
      unsigned K = sh_K, cum = 0u;
      int b = 255;
      for (; b >= 0; b--) {
        cum += hist[b];
        if (cum >= K) break;
      }
      sh_K = K - (cum - hist[b]);
      sh_prefix = prefix | ((unsigned)b << shift);
    }
    __syncthreads();
  }
  const unsigned T = sh_prefix;
  const unsigned Keq = sh_K;
  for (int k = t; k < L; k += 256) {
    if (keys[k] > T) {
      unsigned p = atomicAdd(&sh_cnt, 1u);
      sel[(size_t)s * TOPK_ + p] = k;
    }
  }
  __syncthreads();
  if (t == 0) {
    unsigned base = sh_cnt, taken = 0u;
    for (int k = 0; k < L && taken < Keq; k++) {
      if (keys[k] == T) { sel[(size_t)s * TOPK_ + base + taken] = k; taken++; }
    }
    selcnt[s] = TOPK_;
  }
}

// ---------------- kvp (stride 640) -> kvbf bf16 (stride 576) ----------------
__global__ __launch_bounds__(256) void kv_to_bf16_pad(const float* __restrict__ kvp,
                                                      unsigned short* __restrict__ kvbf) {
  const int s = blockIdx.x, t = threadIdx.x;
  for (int c = t; c < 576; c += 256)
    kvbf[(size_t)s * 576 + c] = f2bf(kvp[(size_t)s * 640 + c]);
}

// ---------------- qfull rope fill: qfull[s][h*576+512+2j..] = bf16(rope(qb)*qscale) ----------------
__global__ __launch_bounds__(256) void qfull_rope(const float* __restrict__ qb,
                                                  unsigned short* __restrict__ qfull) {
  int id = blockIdx.x * 256 + threadIdx.x;  // S*16*32
  int s = id >> 9, r = id & 511, h = r >> 5, j = r & 31;
  const float qscale = 0.07216878364870322f;
  const float* src = qb + (size_t)s * 3072 + h * 192 + 128 + 2 * j;
  unsigned pk = (unsigned)f2bf(src[0] * qscale) | ((unsigned)f2bf(src[1] * qscale) << 16);
  *(unsigned*)(qfull + (size_t)s * 9216 + h * 576 + 512 + 2 * j) = pk;
}

// ---------------- flash attention v5: in-wave softmax + T14 prefetch + kvt2 XOR swizzle ----------------
// Verified R5/R6/R7: conflicts 2.27e7, ~224 us. UNCHANGED this round.
#define KC 32
__global__ __launch_bounds__(256, 3) void flash_attn2(const unsigned short* __restrict__ qfull,
                                                      const unsigned short* __restrict__ kvbf,
                                                      const int* __restrict__ sel,
                                                      unsigned short* __restrict__ o_c) {
  const int s = blockIdx.x, t = threadIdx.x;
  const int lane = t & 63, w = t >> 6;
  const int half = w >> 1, kt = w & 1;
  const int ln = lane & 15, quad = lane >> 4;
  __shared__ unsigned kvt2[288 * 36];        // [c2][key^swz] dword = 2 bf16 (c even, c odd)
  __shared__ float s_part[2][16][36];
  __shared__ unsigned short p_bf[16][40];
  __shared__ float al_sh[16], l_sh[16];
  const int cnt = (s < 1024) ? (s + 1) : 1024;

  bf16x8 qa[9];
  {
    const unsigned short* qrow = qfull + (size_t)s * 9216 + ln * 576 + half * 288 + quad * 8;
#pragma unroll
    for (int kk = 0; kk < 9; kk++) qa[kk] = *(const bf16x8*)(qrow + kk * 32);
  }
  f32x4 o[8];
#pragma unroll
  for (int i = 0; i < 8; i++) o[i] = (f32x4){0.f, 0.f, 0.f, 0.f};
  float m_run = -3.0e38f, l_run = 0.f;
  const int skey = t >> 3, ssub = t & 7;
  const int scol = skey ^ ((ssub & 3) << 3);           // swizzled staging column
  const int keyi = (kt * 16 + ln) ^ (quad << 3);       // swizzled QK read column
  const int pvoff = (quad ^ ((ln >> 2) & 3)) << 3;     // swizzled PV read base

  // prefetch chunk 0
  float4 pf[9];
  bool vld;
  {
    int gk = skey;
    vld = (gk < cnt);
    if (vld) {
      const unsigned short* sp = kvbf + (size_t)sel[(size_t)s * TOPK_ + gk] * 576;
#pragma unroll
      for (int j = 0; j < 9; j++) pf[j] = *(const float4*)(sp + (ssub + 8 * j) * 8);
    }
  }

  for (int k0 = 0; k0 < cnt; k0 += KC) {
    __syncthreads();  // (1) prev chunk consumers done with kvt2
    if (vld) {
#pragma unroll
      for (int j = 0; j < 9; j++) {
        const unsigned* pv = (const unsigned*)&pf[j];
        int base = ((ssub + 8 * j) * 4) * 36 + scol;
        kvt2[base] = pv[0];
        kvt2[base + 36] = pv[1];
        kvt2[base + 72] = pv[2];
        kvt2[base + 108] = pv[3];
      }
    } else {
#pragma unroll
      for (int j = 0; j < 9; j++) {
        int base = ((ssub + 8 * j) * 4) * 36 + scol;
        kvt2[base] = 0u; kvt2[base + 36] = 0u; kvt2[base + 72] = 0u; kvt2[base + 108] = 0u;
      }
    }
    // T14: issue next chunk's gather now; lands during QK/softmax/PV
    {
      int gkn = k0 + KC + skey;
      bool vn = (gkn < cnt);
      if (vn) {
        const unsigned short* sp = kvbf + (size_t)sel[(size_t)s * TOPK_ + gkn] * 576;
#pragma unroll
        for (int j = 0; j < 9; j++) pf[j] = *(const float4*)(sp + (ssub + 8 * j) * 8);
      }
      vld = vn;
    }
    __syncthreads();  // (2) kvt2 ready
    // QK: wave covers K-half `half`, key-tile kt
    {
      f32x4 sacc = (f32x4){0.f, 0.f, 0.f, 0.f};
#pragma unroll
      for (int kk = 0; kk < 9; kk++) {
        int c2b = half * 144 + kk * 16 + quad * 4;
        unsigned bw[4];
        bw[0] = kvt2[c2b * 36 + keyi];
        bw[1] = kvt2[(c2b + 1) * 36 + keyi];
        bw[2] = kvt2[(c2b + 2) * 36 + keyi];
        bw[3] = kvt2[(c2b + 3) * 36 + keyi];
        sacc = __builtin_amdgcn_mfma_f32_16x16x32_bf16(qa[kk], *(const bf16x8*)bw, sacc, 0, 0, 0);
      }
#pragma unroll
      for (int r = 0; r < 4; r++) s_part[half][quad * 4 + r][kt * 16 + ln] = sacc[r];
    }
    __syncthreads();  // (3) s_part ready
    // in-wave softmax: head h = w*4 + quad (16-lane group), keys (2*ln, 2*ln+1)
    {
      const int h = w * 4 + quad;
      float a0 = s_part[0][h][2 * ln] + s_part[1][h][2 * ln];
      float a1 = s_part[0][h][2 * ln + 1] + s_part[1][h][2 * ln + 1];
      float v0 = (k0 + 2 * ln < cnt) ? a0 : -3.0e38f;
      float v1 = (k0 + 2 * ln + 1 < cnt) ? a1 : -3.0e38f;
      float tm = fmaxf(v0, v1);
      tm = fmaxf(tm, __shfl_xor(tm, 1));
      tm = fmaxf(tm, __shfl_xor(tm, 2));
      tm = fmaxf(tm, __shfl_xor(tm, 4));
      tm = fmaxf(tm, __shfl_xor(tm, 8));
      float mn = fmaxf(m_run, tm);
      float alpha = __expf(m_run - mn);
      m_run = mn;
      float p0 = __expf(v0 - mn);
      float p1 = __expf(v1 - mn);
      unsigned pk = (unsigned)f2bf(p0) | ((unsigned)f2bf(p1) << 16);
      *(unsigned*)&p_bf[h][2 * ln] = pk;
      float rs = p0 + p1;
      rs += __shfl_xor(rs, 1);
      rs += __shfl_xor(rs, 2);
      rs += __shfl_xor(rs, 4);
      rs += __shfl_xor(rs, 8);
      l_run = l_run * alpha + rs;
      if (ln == 0) al_sh[h] = alpha;
    }
    __syncthreads();  // (4) p_bf / al_sh ready
    // PV via MFMA: A = P[h][key], B = V[key][c] from c-pair dwords (swizzled key cols)
    {
      bf16x8 pa = *(const bf16x8*)&p_bf[ln][quad * 8];
      float al0 = al_sh[quad * 4 + 0], al1 = al_sh[quad * 4 + 1];
      float al2 = al_sh[quad * 4 + 2], al3 = al_sh[quad * 4 + 3];
#pragma unroll
      for (int i = 0; i < 8; i++) {
        o[i][0] *= al0; o[i][1] *= al1; o[i][2] *= al2; o[i][3] *= al3;
      }
#pragma unroll
      for (int tau = 0; tau < 4; tau++) {
        const unsigned* kp = &kvt2[(w * 64 + tau * 16 + ln) * 36 + pvoff];
        uint4 lo = *(const uint4*)kp;
        uint4 hi = *(const uint4*)(kp + 4);
        unsigned ev[4], od[4];
        ev[0] = __builtin_amdgcn_perm(lo.y, lo.x, 0x05040100u);
        od[0] = __builtin_amdgcn_perm(lo.y, lo.x, 0x07060302u);
        ev[1] = __builtin_amdgcn_perm(lo.w, lo.z, 0x05040100u);
        od[1] = __builtin_amdgcn_perm(lo.w, lo.z, 0x07060302u);
        ev[2] = __builtin_amdgcn_perm(hi.y, hi.x, 0x05040100u);
        od[2] = __builtin_amdgcn_perm(hi.y, hi.x, 0x07060302u);
        ev[3] = __builtin_amdgcn_perm(hi.w, hi.z, 0x05040100u);
        od[3] = __builtin_amdgcn_perm(hi.w, hi.z, 0x07060302u);
        o[tau * 2]     = __builtin_amdgcn_mfma_f32_16x16x32_bf16(pa, *(const bf16x8*)ev, o[tau * 2], 0, 0, 0);
        o[tau * 2 + 1] = __builtin_amdgcn_mfma_f32_16x16x32_bf16(pa, *(const bf16x8*)od, o[tau * 2 + 1], 0, 0, 0);
      }
    }
  }
  // epilogue: final 1/l per head from owner wave, then write-out
  if (ln == 0) l_sh[w * 4 + quad] = 1.0f / l_run;
  __syncthreads();
  {
    float li[4] = {l_sh[quad * 4 + 0], l_sh[quad * 4 + 1], l_sh[quad * 4 + 2], l_sh[quad * 4 + 3]};
#pragma unroll
    for (int tau = 0; tau < 4; tau++) {
      int c2 = w * 64 + tau * 16 + ln;
#pragma unroll
      for (int r = 0; r < 4; r++) {
        int h = quad * 4 + r;
        unsigned pk = (unsigned)f2bf(o[tau * 2][r] * li[r]) |
                      ((unsigned)f2bf(o[tau * 2 + 1][r] * li[r]) << 16);
        *(unsigned*)(o_c + (size_t)s * 8192 + h * 512 + 2 * c2) = pk;
      }
    }
  }
}

// ---------------- launch ----------------
extern "C" void kernel_launch(void* const* d_in, const int* in_sizes, int n_in,
                              void* d_out, int out_size, void* d_ws, size_t ws_size,
                              hipStream_t stream) {
  const float* hs         = (const float*)d_in[0];
  const float* cosp       = (const float*)d_in[1];
  const float* sinp       = (const float*)d_in[2];
  const float* w_q_a      = (const float*)d_in[3];
  const float* q_a_ln_w   = (const float*)d_in[4];
  const float* w_q_b      = (const float*)d_in[5];
  const float* w_kv_a     = (const float*)d_in[6];
  const float* kv_a_ln_w  = (const float*)d_in[7];
  const float* w_kv_b     = (const float*)d_in[8];
  const float* w_o        = (const float*)d_in[9];
  const float* idx_wq_b   = (const float*)d_in[10];
  const float* idx_wk     = (const float*)d_in[11];
  const float* idx_k_ln_w = (const float*)d_in[12];
  const float* idx_k_ln_b = (const float*)d_in[13];
  const float* idx_w_proj = (const float*)d_in[14];
  float* out = (float*)d_out;

  // ---- compact workspace layout (floats); total 45,320,192 f = 181.3 MB ----
  float* ws = (float*)d_ws;
  float*          qb      = ws;                                   // 6,291,456 f
  float*          cq      = ws + 6291456;                         // 3,145,728 f (dead after rmsnorm)
  unsigned short* qbbf    = (unsigned short*)cq;                  //   alias: 3,145,728 sh
  unsigned short* cqbf    = (unsigned short*)(ws + 9437184);      // 3,145,728 sh
  float*          kvp     = ws + 11010048;                        // 1,310,720 f
  unsigned short* kvbf    = (unsigned short*)(ws + 12320768);     // 1,179,648 sh
  float*          wts     = ws + 12910592;                        // 32,768 f
  int*            sel     = (int*)(ws + 12943360);                // 2,097,152 i
  int*            selcnt  = sel + 2097152;                        // 2,048 i
  float*          ki      = ws + 15042560;                        // 262,144 f
  unsigned short* kibf    = (unsigned short*)(ws + 15304704);     // 262,144 sh
  unsigned short* wkvbbf  = (unsigned short*)(ws + 15435776);     // 2,097,152 sh (512x4096)
  unsigned short* wvT     = (unsigned short*)(ws + 16484352);     // 1,048,576 sh
  unsigned short* attnbbf = (unsigned short*)(ws + 17008640);     // 4,194,304 sh
  unsigned short* o_c     = (unsigned short*)(ws + 19105792);     // 16,777,216 sh
  unsigned short* woT     = o_c;                                  //   alias (o_c dead after wv gemm)
  unsigned short* hsbf    = (unsigned short*)(ws + 27494400);     // 8,388,608 sh
  float*          qi      = ws + 31688704;                        // 4,194,304 f
  unsigned short* qibf    = (unsigned short*)(ws + 35883008);     // 4,194,304 sh
  float*          isc     = ws + 37980160;                        // 4,194,304 f
  unsigned short* qfull   = (unsigned short*)qi;                  //   alias (dead after topk)
  unsigned short* wT      = (unsigned short*)(ws + 42174464);     // 6,291,456 sh transpose scratch

  const float qscale = 0.07216878364870322f;  // 192^-0.5

  // 1. casts / cq path (cq: split-K x4 -> 768 blocks)
  cast_bf16<<<4096, 256, 0, stream>>>(hs, hsbf);
  transpose_cast<<<dim3(48, 64), 256, 0, stream>>>(w_q_a, wT, 4096, 1536);
  hipMemsetAsync(cq, 0, (size_t)2048 * 1536 * 4, stream);
  gemm_bf16x_sk<<<dim3(12, 16, 4), 256, 0, stream>>>(hsbf, wT, cq, 1024, 4096, 4096, 1536);
  rmsnorm_bf16_kernel<<<2048, 256, 0, stream>>>(cq, q_a_ln_w, cqbf, 1536, 1536);

  // 2. indexer path (qi: split-K x2 -> 512 blocks; ki: x16 -> 256 blocks)
  transpose_cast<<<dim3(64, 24), 256, 0, stream>>>(idx_wq_b, wT, 1536, 2048);
  hipMemsetAsync(qi, 0, (size_t)2048 * 2048 * 4, stream);
  gemm_bf16x_sk<<<dim3(16, 16, 2), 256, 0, stream>>>(cqbf, wT, qi, 768, 1536, 1536, 2048);
  rope_qi_nonint<<<4096, 256, 0, stream>>>(qi, cosp, sinp);
  cast_bf16<<<2048, 256, 0, stream>>>(qi, qibf);
  transpose_cast<<<dim3(4, 64), 256, 0, stream>>>(idx_wk, wT, 4096, 128);
  hipMemsetAsync(ki, 0, (size_t)2048 * 128 * 4, stream);
  gemm_bf16x_sk<<<dim3(1, 16, 16), 256, 0, stream>>>(hsbf, wT, ki, 256, 4096, 4096, 128);
  layernorm128_kernel<<<2048, 128, 0, stream>>>(ki, idx_k_ln_w, idx_k_ln_b);
  rope_ki_nonint<<<256, 256, 0, stream>>>(ki, cosp, sinp);
  cast_bf16<<<128, 256, 0, stream>>>(ki, kibf);
  wts_kernel<<<2048, 256, 0, stream>>>(hs, idx_w_proj, wts);
  indexer_mfma<<<528, 256, 0, stream>>>(qibf, kibf, wts, isc);
  topk_select<<<2048, 256, 0, stream>>>(isc, sel, selcnt);

  // 3. q path (qb: split-K x2 -> 768 blocks)
  transpose_cast<<<dim3(96, 24), 256, 0, stream>>>(w_q_b, wT, 1536, 3072);
  hipMemsetAsync(qb, 0, (size_t)2048 * 3072 * 4, stream);
  gemm_bf16x_sk<<<dim3(24, 16, 2), 256, 0, stream>>>(cqbf, wT, qb, 768, 1536, 1536, 3072);
  rope_q_inter<<<4096, 256, 0, stream>>>(qb, cosp, sinp);
  cast_bf16<<<3072, 256, 0, stream>>>(qb, qbbf);

  // 4. kv path (padded N=640; split-K x8 -> 640 blocks)
  transpose_cast<<<dim3(20, 64), 256, 0, stream>>>(w_kv_a, wT, 4096, 576);
  hipMemsetAsync(kvp, 0, (size_t)2048 * 640 * 4, stream);
  gemm_bf16x_sk<<<dim3(5, 16, 8), 256, 0, stream>>>(hsbf, wT, kvp, 512, 4096, 4096, 640);
  rmsnorm_kernel<<<2048, 256, 0, stream>>>(kvp, kv_a_ln_w, 512, 640);
  rope_k_inter<<<256, 256, 0, stream>>>(kvp, cosp, sinp, 640);
  kv_to_bf16_pad<<<2048, 256, 0, stream>>>(kvp, kvbf);

  // 5. absorbed q: qfull[s][h*576 + 0..511] = (q_nope @ w_k[h]^T)*qscale ; [512..575] = rope*qscale
  cast_bf16<<<1024, 256, 0, stream>>>(w_kv_b, wkvbbf);
  gemm_bf16x_bf<<<dim3(4, 16, 16), 256, 0, stream>>>(qbbf, wkvbbf, qfull,
                                                     128, 3072, 4096, 9216, 192, 256, 576, qscale);
  qfull_rope<<<4096, 256, 0, stream>>>(qb, qfull);

  // 6. flash attention
  flash_attn2<<<2048, 256, 0, stream>>>(qfull, kvbf, sel, o_c);

  // 7. attn_out[s][h*128+d] = o_c[s][h*512+:] @ w_v[h]
  transpose_wv<<<dim3(4, 16), 256, 0, stream>>>(wkvbbf, wvT);
  gemm_bf16x_bf<<<dim3(1, 16, 16), 256, 0, stream>>>(o_c, wvT, attnbbf,
                                                     512, 8192, 512, 2048, 512, 65536, 128, 1.0f);

  // 8. out = attn_out @ w_o (split-K x2 -> 1024 blocks; out must be re-zeroed every replay)
  transpose_cast<<<dim3(128, 32), 256, 0, stream>>>(w_o, woT, 2048, 4096);
  hipMemsetAsync(out, 0, (size_t)2048 * 4096 * 4, stream);
  gemm_bf16x_sk<<<dim3(32, 16, 2), 256, 0, stream>>>(attnbbf, woT, out, 1024, 2048, 2048, 4096);
}

// Round 10
// 958.055 us; speedup vs baseline: 1.1190x; 1.1190x over previous
//
#include <hip/hip_runtime.h>
#include <math.h>

// Shapes (B=1 throughout)
#define S_LEN 2048
#define D_MODEL 4096
#define NH 16
#define TOPK_ 1024

typedef float f32x4 __attribute__((ext_vector_type(4)));
typedef short bf16x8 __attribute__((ext_vector_type(8)));

__device__ __forceinline__ unsigned short f2bf(float f) {
  unsigned u = __float_as_uint(f);
  u += 0x7fffu + ((u >> 16) & 1u);  // RNE
  return (unsigned short)(u >> 16);
}

// async global->LDS, 16B per lane. LDS dest = wave-uniform base + lane*16 (m97 pattern).
__device__ __forceinline__ void gload16(const unsigned short* g, unsigned short* l) {
  __builtin_amdgcn_global_load_lds(
      (const __attribute__((address_space(1))) unsigned int*)g,
      (__attribute__((address_space(3))) unsigned int*)l, 16, 0, 0);
}

// ---------------- generalized bf16 MFMA GEMM: C[M,N] = A[M,K] @ Bt[N,K]^T ----------------
// Tile 128x128, BK=32, 256 threads. Double-buffered global_load_lds staging (R6/R7 verified).
__global__ __launch_bounds__(256) void gemm_bf16x(const unsigned short* __restrict__ A,
                                                  const unsigned short* __restrict__ Bt,
                                                  float* __restrict__ C,
                                                  int K, int lda, int ldb, int ldc,
                                                  int za, int zb, int zc) {
  A += (size_t)blockIdx.z * za;
  Bt += (size_t)blockIdx.z * zb;
  C += (size_t)blockIdx.z * zc;
  __shared__ __align__(16) unsigned short As[2][128 * 32];
  __shared__ __align__(16) unsigned short Bs[2][128 * 32];
  const int t = threadIdx.x, lane = t & 63, w = t >> 6;
  const int m0 = blockIdx.y * 128, n0 = blockIdx.x * 128;
  const int mb = (w & 1) * 64, nb = (w >> 1) * 64;
  const int fr = lane & 15, fq = lane >> 4;
  f32x4 acc[4][4];
#pragma unroll
  for (int i = 0; i < 4; i++)
#pragma unroll
    for (int j = 0; j < 4; j++) acc[i][j] = (f32x4){0.f, 0.f, 0.f, 0.f};
  const int grow = t >> 2, gsub = (t & 3) * 8;
  const int wb = w * 512;
  const unsigned short* AgL = A + (size_t)(m0 + grow) * lda + gsub;
  const unsigned short* AgH = A + (size_t)(m0 + 64 + grow) * lda + gsub;
  const unsigned short* BgL = Bt + (size_t)(n0 + grow) * ldb + gsub;
  const unsigned short* BgH = Bt + (size_t)(n0 + 64 + grow) * ldb + gsub;
  gload16(AgL, &As[0][wb]);
  gload16(AgH, &As[0][2048 + wb]);
  gload16(BgL, &Bs[0][wb]);
  gload16(BgH, &Bs[0][2048 + wb]);
  int cur = 0;
  for (int k0 = 0; k0 < K; k0 += 32) {
    __syncthreads();
    if (k0 + 32 < K) {
      gload16(AgL + k0 + 32, &As[cur ^ 1][wb]);
      gload16(AgH + k0 + 32, &As[cur ^ 1][2048 + wb]);
      gload16(BgL + k0 + 32, &Bs[cur ^ 1][wb]);
      gload16(BgH + k0 + 32, &Bs[cur ^ 1][2048 + wb]);
    }
    bf16x8 af[4], bfr[4];
#pragma unroll
    for (int mt = 0; mt < 4; mt++) af[mt] = *(const bf16x8*)&As[cur][(mb + mt * 16 + fr) * 32 + fq * 8];
#pragma unroll
    for (int nt = 0; nt < 4; nt++) bfr[nt] = *(const bf16x8*)&Bs[cur][(nb + nt * 16 + fr) * 32 + fq * 8];
#pragma unroll
    for (int mt = 0; mt < 4; mt++)
#pragma unroll
      for (int nt = 0; nt < 4; nt++)
        acc[mt][nt] = __builtin_amdgcn_mfma_f32_16x16x32_bf16(af[mt], bfr[nt], acc[mt][nt], 0, 0, 0);
    cur ^= 1;
  }
#pragma unroll
  for (int mt = 0; mt < 4; mt++) {
#pragma unroll
    for (int r = 0; r < 4; r++) {
      int row = m0 + mb + mt * 16 + fq * 4 + r;
      float* cp = C + (size_t)row * ldc + n0 + nb + fr;
#pragma unroll
      for (int nt = 0; nt < 4; nt++) cp[nt * 16] = acc[mt][nt][r];
    }
  }
}

// same, bf16 output with scale
__global__ __launch_bounds__(256) void gemm_bf16x_bf(const unsigned short* __restrict__ A,
                                                     const unsigned short* __restrict__ Bt,
                                                     unsigned short* __restrict__ C,
                                                     int K, int lda, int ldb, int ldc,
                                                     int za, int zb, int zc, float scale) {
  A += (size_t)blockIdx.z * za;
  Bt += (size_t)blockIdx.z * zb;
  C += (size_t)blockIdx.z * zc;
  __shared__ __align__(16) unsigned short As[2][128 * 32];
  __shared__ __align__(16) unsigned short Bs[2][128 * 32];
  const int t = threadIdx.x, lane = t & 63, w = t >> 6;
  const int m0 = blockIdx.y * 128, n0 = blockIdx.x * 128;
  const int mb = (w & 1) * 64, nb = (w >> 1) * 64;
  const int fr = lane & 15, fq = lane >> 4;
  f32x4 acc[4][4];
#pragma unroll
  for (int i = 0; i < 4; i++)
#pragma unroll
    for (int j = 0; j < 4; j++) acc[i][j] = (f32x4){0.f, 0.f, 0.f, 0.f};
  const int grow = t >> 2, gsub = (t & 3) * 8;
  const int wb = w * 512;
  const unsigned short* AgL = A + (size_t)(m0 + grow) * lda + gsub;
  const unsigned short* AgH = A + (size_t)(m0 + 64 + grow) * lda + gsub;
  const unsigned short* BgL = Bt + (size_t)(n0 + grow) * ldb + gsub;
  const unsigned short* BgH = Bt + (size_t)(n0 + 64 + grow) * ldb + gsub;
  gload16(AgL, &As[0][wb]);
  gload16(AgH, &As[0][2048 + wb]);
  gload16(BgL, &Bs[0][wb]);
  gload16(BgH, &Bs[0][2048 + wb]);
  int cur = 0;
  for (int k0 = 0; k0 < K; k0 += 32) {
    __syncthreads();
    if (k0 + 32 < K) {
      gload16(AgL + k0 + 32, &As[cur ^ 1][wb]);
      gload16(AgH + k0 + 32, &As[cur ^ 1][2048 + wb]);
      gload16(BgL + k0 + 32, &Bs[cur ^ 1][wb]);
      gload16(BgH + k0 + 32, &Bs[cur ^ 1][2048 + wb]);
    }
    bf16x8 af[4], bfr[4];
#pragma unroll
    for (int mt = 0; mt < 4; mt++) af[mt] = *(const bf16x8*)&As[cur][(mb + mt * 16 + fr) * 32 + fq * 8];
#pragma unroll
    for (int nt = 0; nt < 4; nt++) bfr[nt] = *(const bf16x8*)&Bs[cur][(nb + nt * 16 + fr) * 32 + fq * 8];
#pragma unroll
    for (int mt = 0; mt < 4; mt++)
#pragma unroll
      for (int nt = 0; nt < 4; nt++)
        acc[mt][nt] = __builtin_amdgcn_mfma_f32_16x16x32_bf16(af[mt], bfr[nt], acc[mt][nt], 0, 0, 0);
    cur ^= 1;
  }
#pragma unroll
  for (int mt = 0; mt < 4; mt++) {
#pragma unroll
    for (int r = 0; r < 4; r++) {
      int row = m0 + mb + mt * 16 + fq * 4 + r;
      unsigned short* cp = C + (size_t)row * ldc + n0 + nb + fr;
#pragma unroll
      for (int nt = 0; nt < 4; nt++) cp[nt * 16] = f2bf(acc[mt][nt][r] * scale);
    }
  }
}

// split-K: blockIdx.z = K-chunk; partials atomicAdd'ed into PRE-ZEROED fp32 C.
// R7-validated; R8 lesson: only for occupancy-starved shapes (<1 block/CU), shallow factors.
__global__ __launch_bounds__(256) void gemm_bf16x_sk(const unsigned short* __restrict__ A,
                                                     const unsigned short* __restrict__ Bt,
                                                     float* __restrict__ C,
                                                     int Kc, int lda, int ldb, int ldc) {
  const int kbase = blockIdx.z * Kc;
  __shared__ __align__(16) unsigned short As[2][128 * 32];
  __shared__ __align__(16) unsigned short Bs[2][128 * 32];
  const int t = threadIdx.x, lane = t & 63, w = t >> 6;
  const int m0 = blockIdx.y * 128, n0 = blockIdx.x * 128;
  const int mb = (w & 1) * 64, nb = (w >> 1) * 64;
  const int fr = lane & 15, fq = lane >> 4;
  f32x4 acc[4][4];
#pragma unroll
  for (int i = 0; i < 4; i++)
#pragma unroll
    for (int j = 0; j < 4; j++) acc[i][j] = (f32x4){0.f, 0.f, 0.f, 0.f};
  const int grow = t >> 2, gsub = (t & 3) * 8;
  const int wb = w * 512;
  const unsigned short* AgL = A + (size_t)(m0 + grow) * lda + kbase + gsub;
  const unsigned short* AgH = A + (size_t)(m0 + 64 + grow) * lda + kbase + gsub;
  const unsigned short* BgL = Bt + (size_t)(n0 + grow) * ldb + kbase + gsub;
  const unsigned short* BgH = Bt + (size_t)(n0 + 64 + grow) * ldb + kbase + gsub;
  gload16(AgL, &As[0][wb]);
  gload16(AgH, &As[0][2048 + wb]);
  gload16(BgL, &Bs[0][wb]);
  gload16(BgH, &Bs[0][2048 + wb]);
  int cur = 0;
  for (int k0 = 0; k0 < Kc; k0 += 32) {
    __syncthreads();
    if (k0 + 32 < Kc) {
      gload16(AgL + k0 + 32, &As[cur ^ 1][wb]);
      gload16(AgH + k0 + 32, &As[cur ^ 1][2048 + wb]);
      gload16(BgL + k0 + 32, &Bs[cur ^ 1][wb]);
      gload16(BgH + k0 + 32, &Bs[cur ^ 1][2048 + wb]);
    }
    bf16x8 af[4], bfr[4];
#pragma unroll
    for (int mt = 0; mt < 4; mt++) af[mt] = *(const bf16x8*)&As[cur][(mb + mt * 16 + fr) * 32 + fq * 8];
#pragma unroll
    for (int nt = 0; nt < 4; nt++) bfr[nt] = *(const bf16x8*)&Bs[cur][(nb + nt * 16 + fr) * 32 + fq * 8];
#pragma unroll
    for (int mt = 0; mt < 4; mt++)
#pragma unroll
      for (int nt = 0; nt < 4; nt++)
        acc[mt][nt] = __builtin_amdgcn_mfma_f32_16x16x32_bf16(af[mt], bfr[nt], acc[mt][nt], 0, 0, 0);
    cur ^= 1;
  }
#pragma unroll
  for (int mt = 0; mt < 4; mt++) {
#pragma unroll
    for (int r = 0; r < 4; r++) {
      int row = m0 + mb + mt * 16 + fq * 4 + r;
      float* cp = C + (size_t)row * ldc + n0 + nb + fr;
#pragma unroll
      for (int nt = 0; nt < 4; nt++) atomicAdd(cp + nt * 16, acc[mt][nt][r]);
    }
  }
}

// ---------------- cast fp32 -> bf16 (8 elems/thread) ----------------
__global__ __launch_bounds__(256) void cast_bf16(const float* __restrict__ in,
                                                 unsigned short* __restrict__ out) {
  size_t i = (size_t)(blockIdx.x * 256 + threadIdx.x) * 8;
  float4 v0 = *(const float4*)(in + i);
  float4 v1 = *(const float4*)(in + i + 4);
  unsigned short tmp[8] = {f2bf(v0.x), f2bf(v0.y), f2bf(v0.z), f2bf(v0.w),
                           f2bf(v1.x), f2bf(v1.y), f2bf(v1.z), f2bf(v1.w)};
  *(float4*)(out + i) = *(float4*)tmp;
}

// ---------------- transpose+cast: in fp32 [K,N] -> out bf16 [Npad,K] ----------------
__global__ __launch_bounds__(256) void transpose_cast(const float* __restrict__ in,
                                                      unsigned short* __restrict__ out,
                                                      int K, int N) {
  __shared__ float buf[64][33];
  const int k0 = blockIdx.y * 64, n0 = blockIdx.x * 32;
  const int t = threadIdx.x;
  const bool valid = (n0 < N);
  if (valid) {
#pragma unroll
    for (int i = 0; i < 2; i++) {
      int c = i * 256 + t;
      int kk = c >> 3, nn = (c & 7) * 4;
      float4 v = *(const float4*)(in + (size_t)(k0 + kk) * N + n0 + nn);
      buf[kk][nn] = v.x; buf[kk][nn + 1] = v.y; buf[kk][nn + 2] = v.z; buf[kk][nn + 3] = v.w;
    }
  }
  __syncthreads();
  const int n = t >> 3, k8 = (t & 7) * 8;
  unsigned short tmp[8];
#pragma unroll
  for (int j = 0; j < 8; j++) tmp[j] = valid ? f2bf(buf[k8 + j][n]) : (unsigned short)0;
  *(float4*)(out + (size_t)(n0 + n) * K + k0 + k8) = *(float4*)tmp;
}

// ---------------- transpose w_v slice: wvT[h][d][c] = wkvbbf[c][h*256+128+d] ----------------
__global__ __launch_bounds__(256) void transpose_wv(const unsigned short* __restrict__ wkvbbf,
                                                    unsigned short* __restrict__ wvT) {
  __shared__ unsigned short tile[128][136];
  const int c0 = blockIdx.x * 128, h = blockIdx.y;
  const int t = threadIdx.x;
  for (int i = t; i < 128 * 16; i += 256) {
    int c = i >> 4, sub = (i & 15) * 8;
    *(float4*)&tile[c][sub] = *(const float4*)(wkvbbf + (size_t)(c0 + c) * 4096 + h * 256 + 128 + sub);
  }
  __syncthreads();
  for (int i = t; i < 128 * 16; i += 256) {
    int d = i >> 4, cs = (i & 15) * 8;
    unsigned short tmp[8];
#pragma unroll
    for (int j = 0; j < 8; j++) tmp[j] = tile[cs + j][d];
    *(float4*)(wvT + (size_t)h * 65536 + (size_t)d * 512 + c0 + cs) = *(float4*)tmp;
  }
}

// ---------------- RMSNorm in place ----------------
__global__ __launch_bounds__(256) void rmsnorm_kernel(float* __restrict__ x,
                                                      const float* __restrict__ w,
                                                      int ncol, int stride) {
  const int s = blockIdx.x, t = threadIdx.x;
  float* row = x + (size_t)s * stride;
  float ss = 0.f;
  for (int d = t; d < ncol; d += 256) { float v = row[d]; ss += v * v; }
  __shared__ float red[256];
  red[t] = ss;
  __syncthreads();
  for (int o = 128; o > 0; o >>= 1) { if (t < o) red[t] += red[t + o]; __syncthreads(); }
  float r = 1.0f / sqrtf(red[0] / (float)ncol + 1e-6f);
  for (int d = t; d < ncol; d += 256) row[d] = row[d] * r * w[d];
}

// RMSNorm in place + bf16 copy out
__global__ __launch_bounds__(256) void rmsnorm_bf16_kernel(float* __restrict__ x,
                                                           const float* __restrict__ w,
                                                           unsigned short* __restrict__ xbf,
                                                           int ncol, int stride) {
  const int s = blockIdx.x, t = threadIdx.x;
  float* row = x + (size_t)s * stride;
  float ss = 0.f;
  for (int d = t; d < ncol; d += 256) { float v = row[d]; ss += v * v; }
  __shared__ float red[256];
  red[t] = ss;
  __syncthreads();
  for (int o = 128; o > 0; o >>= 1) { if (t < o) red[t] += red[t + o]; __syncthreads(); }
  float r = 1.0f / sqrtf(red[0] / (float)ncol + 1e-6f);
  for (int d = t; d < ncol; d += 256) {
    float v = row[d] * r * w[d];
    row[d] = v;
    xbf[(size_t)s * ncol + d] = f2bf(v);
  }
}

// ---------------- fused LayerNorm + noninterleaved rope + bf16 cast (ki path) ----------------
// 128 threads; rope pair (j, j+32) both live in wave 0 -> one shfl_xor(32). ki fp32 not written back (dead).
__global__ __launch_bounds__(128) void layernorm_rope_cast(const float* __restrict__ x,
                                                           const float* __restrict__ w,
                                                           const float* __restrict__ b,
                                                           const float* __restrict__ cosp,
                                                           const float* __restrict__ sinp,
                                                           unsigned short* __restrict__ kibf) {
  const int s = blockIdx.x, t = threadIdx.x;
  const float* row = x + (size_t)s * 128;
  __shared__ float red[128];
  float v = row[t];
  red[t] = v;
  __syncthreads();
  for (int o = 64; o > 0; o >>= 1) { if (t < o) red[t] += red[t + o]; __syncthreads(); }
  float mu = red[0] / 128.f;
  __syncthreads();
  float d = v - mu;
  red[t] = d * d;
  __syncthreads();
  for (int o = 64; o > 0; o >>= 1) { if (t < o) red[t] += red[t + o]; __syncthreads(); }
  float var = red[0] / 128.f;
  float y = d * (1.0f / sqrtf(var + 1e-5f)) * w[t] + b[t];
  float part = __shfl_xor(y, 32);  // partner within wave 0 (t<64)
  float res = y;
  if (t < 64) {
    int j = t & 31;
    float c = cosp[s * 32 + j], sn = sinp[s * 32 + j];
    res = (t < 32) ? (y * c - part * sn) : (part * sn + y * c);
  }
  kibf[(size_t)s * 128 + t] = f2bf(res);
}

// ---------------- fused noninterleaved rope + bf16 cast (qi path) ----------------
// One row per block in LDS; replaces rope_qi_nonint + cast_bf16(qi) (saves a full fp32 r/w pass).
__global__ __launch_bounds__(256) void rope_cast_qi(const float* __restrict__ qi,
                                                    const float* __restrict__ cosp,
                                                    const float* __restrict__ sinp,
                                                    unsigned short* __restrict__ qibf) {
  __shared__ float row[2048];
  const int s = blockIdx.x, t = threadIdx.x;
  const float* src = qi + (size_t)s * 2048;
  *(float4*)&row[t * 8] = *(const float4*)(src + t * 8);
  *(float4*)&row[t * 8 + 4] = *(const float4*)(src + t * 8 + 4);
  __syncthreads();
#pragma unroll
  for (int p = 0; p < 2; p++) {
    int id = p * 256 + t;
    int n = id >> 5, j = id & 31;
    float c = cosp[s * 32 + j], sn = sinp[s * 32 + j];
    float xr = row[n * 128 + j], xi = row[n * 128 + j + 32];
    row[n * 128 + j] = xr * c - xi * sn;
    row[n * 128 + j + 32] = xr * sn + xi * c;
  }
  __syncthreads();
  unsigned short tmp[8];
#pragma unroll
  for (int j = 0; j < 8; j++) tmp[j] = f2bf(row[t * 8 + j]);
  *(float4*)(qibf + (size_t)s * 2048 + t * 8) = *(float4*)tmp;
}

// ---------------- fused interleaved rope + bf16 cast + qfull rope-fill (q path) ----------------
// Replaces rope_q_inter + cast_bf16(qb) + qfull_rope. qb fp32 not written back (only the step-5
// GEMM reads qbbf, and only its K=128 nope cols; qfull rope section written here directly).
__global__ __launch_bounds__(256) void rope_cast_q(const float* __restrict__ qb,
                                                   const float* __restrict__ cosp,
                                                   const float* __restrict__ sinp,
                                                   unsigned short* __restrict__ qbbf,
                                                   unsigned short* __restrict__ qfull) {
  __shared__ float row[3072];
  const int s = blockIdx.x, t = threadIdx.x;
  const float qscale = 0.07216878364870322f;
  const float* src = qb + (size_t)s * 3072;
#pragma unroll
  for (int i = 0; i < 3; i++) {
    int c0 = (i * 256 + t) * 4;
    *(float4*)&row[c0] = *(const float4*)(src + c0);
  }
  __syncthreads();
#pragma unroll
  for (int p = 0; p < 2; p++) {
    int id = p * 256 + t;
    int h = id >> 5, j = id & 31;
    float c = cosp[s * 32 + j], sn = sinp[s * 32 + j];
    int base = h * 192 + 128 + 2 * j;
    float x0 = row[base], x1 = row[base + 1];
    float r0 = x0 * c - x1 * sn;
    float r1 = x0 * sn + x1 * c;
    row[base] = r0;
    row[base + 1] = r1;
    unsigned pk = (unsigned)f2bf(r0 * qscale) | ((unsigned)f2bf(r1 * qscale) << 16);
    *(unsigned*)(qfull + (size_t)s * 9216 + h * 576 + 512 + 2 * j) = pk;
  }
  __syncthreads();
  {
    unsigned short tmp[8];
    int c0 = t * 8;
#pragma unroll
    for (int j = 0; j < 8; j++) tmp[j] = f2bf(row[c0 + j]);
    *(float4*)(qbbf + (size_t)s * 3072 + c0) = *(float4*)tmp;
    if (t < 128) {
      int c1 = 2048 + t * 8;
#pragma unroll
      for (int j = 0; j < 8; j++) tmp[j] = f2bf(row[c1 + j]);
      *(float4*)(qbbf + (size_t)s * 3072 + c1) = *(float4*)tmp;
    }
  }
}

// ---------------- RoPE kernel (kv path, kept) ----------------
__global__ __launch_bounds__(256) void rope_k_inter(float* __restrict__ kv,
                                                    const float* __restrict__ cosp,
                                                    const float* __restrict__ sinp,
                                                    int stride) {
  int id = blockIdx.x * 256 + threadIdx.x;
  int s = id >> 5, j = id & 31;
  float c = cosp[s * 32 + j], sn = sinp[s * 32 + j];
  float* base = kv + (size_t)s * stride + 512 + 2 * j;
  float x0 = base[0], x1 = base[1];
  base[0] = x0 * c - x1 * sn;
  base[1] = x0 * sn + x1 * c;
}

// ---------------- wts = hidden @ idx_w_proj * (0.25 * 128^-0.5)  (iscale folded) ----------------
__global__ __launch_bounds__(256) void wts_kernel(const float* __restrict__ hs,
                                                  const float* __restrict__ wp,
                                                  float* __restrict__ wts) {
  const int s = blockIdx.x, t = threadIdx.x;
  float acc[16] = {};
  for (int d = t; d < D_MODEL; d += 256) {
    float h = hs[(size_t)s * D_MODEL + d];
    const float* w = wp + (size_t)d * 16;
#pragma unroll
    for (int n = 0; n < 16; n++) acc[n] += h * w[n];
  }
  __shared__ float red[16][256];
#pragma unroll
  for (int n = 0; n < 16; n++) red[n][t] = acc[n];
  __syncthreads();
  for (int o = 128; o > 0; o >>= 1) {
    if (t < o) {
#pragma unroll
      for (int n = 0; n < 16; n++) red[n][t] += red[n][t + o];
    }
    __syncthreads();
  }
  if (t < 16) wts[(size_t)s * 16 + t] = red[t][0] * 0.022097086912079613f;
}

// ---------------- indexer scores via MFMA, 64x64 lower-tri tiles ----------------
__global__ __launch_bounds__(256) void indexer_mfma(const unsigned short* __restrict__ qibf,
                                                    const unsigned short* __restrict__ kibf,
                                                    const float* __restrict__ wts,
                                                    float* __restrict__ isc) {
  __shared__ unsigned short kis[64 * 136];
  __shared__ unsigned short qis[64 * 136];
  __shared__ float wt_s[64 * 16];
  const int t = threadIdx.x, lane = t & 63, w = t >> 6;
  const int ln = lane & 15, quad = lane >> 4;
  int b = blockIdx.x;
  int qt = (int)((sqrtf(8.0f * b + 1.0f) - 1.0f) * 0.5f);
  while ((qt + 1) * (qt + 2) / 2 <= b) qt++;
  while (qt * (qt + 1) / 2 > b) qt--;
  const int kt = b - qt * (qt + 1) / 2;
  const int q0 = qt * 64, k0 = kt * 64;
#pragma unroll
  for (int p = 0; p < 4; p++) {
    int i = t + p * 256;
    int row = i >> 4, sub = (i & 15) * 8;
    *(float4*)&kis[row * 136 + sub] = *(const float4*)(kibf + (size_t)(k0 + row) * 128 + sub);
  }
  {
    int rw = t >> 2, n4 = (t & 3) * 4;
    *(float4*)&wt_s[rw * 16 + n4] = *(const float4*)(wts + (size_t)(q0 + rw) * 16 + n4);
  }
  __syncthreads();
  bf16x8 kb[4][4];
#pragma unroll
  for (int nt = 0; nt < 4; nt++)
#pragma unroll
    for (int kk = 0; kk < 4; kk++)
      kb[nt][kk] = *(const bf16x8*)&kis[(nt * 16 + ln) * 136 + kk * 32 + quad * 8];
  f32x4 iacc[4];
#pragma unroll
  for (int nt = 0; nt < 4; nt++) iacc[nt] = (f32x4){0.f, 0.f, 0.f, 0.f};

  for (int n = 0; n < 16; n++) {
    __syncthreads();
#pragma unroll
    for (int p = 0; p < 4; p++) {
      int i = t + p * 256;
      int row = i >> 4, sub = (i & 15) * 8;
      *(float4*)&qis[row * 136 + sub] =
          *(const float4*)(qibf + (size_t)(q0 + row) * 2048 + n * 128 + sub);
    }
    __syncthreads();
    bf16x8 qa[4];
#pragma unroll
    for (int kk = 0; kk < 4; kk++)
      qa[kk] = *(const bf16x8*)&qis[(w * 16 + ln) * 136 + kk * 32 + quad * 8];
    float wv0 = wt_s[(w * 16 + quad * 4 + 0) * 16 + n];
    float wv1 = wt_s[(w * 16 + quad * 4 + 1) * 16 + n];
    float wv2 = wt_s[(w * 16 + quad * 4 + 2) * 16 + n];
    float wv3 = wt_s[(w * 16 + quad * 4 + 3) * 16 + n];
#pragma unroll
    for (int nt = 0; nt < 4; nt++) {
      f32x4 sacc = (f32x4){0.f, 0.f, 0.f, 0.f};
#pragma unroll
      for (int kk = 0; kk < 4; kk++)
        sacc = __builtin_amdgcn_mfma_f32_16x16x32_bf16(qa[kk], kb[nt][kk], sacc, 0, 0, 0);
      iacc[nt][0] += fmaxf(sacc[0], 0.f) * wv0;
      iacc[nt][1] += fmaxf(sacc[1], 0.f) * wv1;
      iacc[nt][2] += fmaxf(sacc[2], 0.f) * wv2;
      iacc[nt][3] += fmaxf(sacc[3], 0.f) * wv3;
    }
  }
#pragma unroll
  for (int nt = 0; nt < 4; nt++) {
#pragma unroll
    for (int r = 0; r < 4; r++) {
      int qg = q0 + w * 16 + quad * 4 + r;
      int kg = k0 + nt * 16 + ln;
      isc[(size_t)qg * 2048 + kg] = (kg <= qg) ? iacc[nt][r] : -1.0e30f;
    }
  }
}

// ---------------- exact top-1024 per row (jax tie semantics) ----------------
__global__ __launch_bounds__(256) void topk_select(const float* __restrict__ sc,
                                                   int* __restrict__ sel,
                                                   int* __restrict__ selcnt) {
  const int s = blockIdx.x, t = threadIdx.x;
  if (s < TOPK_) {
    for (int k = t; k <= s; k += 256) sel[(size_t)s * TOPK_ + k] = k;
    if (t == 0) selcnt[s] = s + 1;
    return;
  }
  __shared__ unsigned keys[2048];
  __shared__ unsigned hist[256];
  __shared__ unsigned sh_prefix, sh_K, sh_cnt;
  const int L = s + 1;
  for (int k = t; k < L; k += 256) {
    unsigned u = __float_as_uint(sc[(size_t)s * 2048 + k]);
    u = (u & 0x80000000u) ? ~u : (u | 0x80000000u);
    keys[k] = u;
  }
  if (t == 0) { sh_prefix = 0u; sh_K = TOPK_; sh_cnt = 0u; }
  __syncthreads();
#pragma unroll
  for (int pass = 0; pass < 4; pass++) {
    const int shift = 24 - 8 * pass;
    const unsigned mask_hi = (pass == 0) ? 0u : (0xFFFFFFFFu << (shift + 8));
    hist[t] = 0u;
    __syncthreads();
    unsigned prefix = sh_prefix;
    for (int k = t; k < L; k += 256) {
      unsigned u = keys[k];
      if ((u & mask_hi) == prefix) atomicAdd(&hist[(u >> shift) & 255u], 1u);
    }
    __syncthreads();
    if (t == 0) {
      unsigned K = sh_K, cum = 0u;
      int b = 255;
      for (; b >= 0; b--) {
        cum += hist[b];
        if (cum >= K) break;
      }
      sh_K = K - (cum - hist[b]);
      sh_prefix = prefix | ((unsigned)b << shift);
    }
    __syncthreads();
  }
  const unsigned T = sh_prefix;
  const unsigned Keq = sh_K;
  for (int k = t; k < L; k += 256) {
    if (keys[k] > T) {
      unsigned p = atomicAdd(&sh_cnt, 1u);
      sel[(size_t)s * TOPK_ + p] = k;
    }
  }
  __syncthreads();
  if (t == 0) {
    unsigned base = sh_cnt, taken = 0u;
    for (int k = 0; k < L && taken < Keq; k++) {
      if (keys[k] == T) { sel[(size_t)s * TOPK_ + base + taken] = k; taken++; }
    }
    selcnt[s] = TOPK_;
  }
}

// ---------------- kvp (stride 640) -> kvbf bf16 (stride 576) ----------------
__global__ __launch_bounds__(256) void kv_to_bf16_pad(const float* __restrict__ kvp,
                                                      unsigned short* __restrict__ kvbf) {
  const int s = blockIdx.x, t = threadIdx.x;
  for (int c = t; c < 576; c += 256)
    kvbf[(size_t)s * 576 + c] = f2bf(kvp[(size_t)s * 640 + c]);
}

// ---------------- flash attention v5: in-wave softmax + T14 prefetch + kvt2 XOR swizzle ----------------
// Verified R5/R6/R7: conflicts 2.27e7, ~224 us. UNCHANGED.
#define KC 32
__global__ __launch_bounds__(256, 3) void flash_attn2(const unsigned short* __restrict__ qfull,
                                                      const unsigned short* __restrict__ kvbf,
                                                      const int* __restrict__ sel,
                                                      unsigned short* __restrict__ o_c) {
  const int s = blockIdx.x, t = threadIdx.x;
  const int lane = t & 63, w = t >> 6;
  const int half = w >> 1, kt = w & 1;
  const int ln = lane & 15, quad = lane >> 4;
  __shared__ unsigned kvt2[288 * 36];        // [c2][key^swz] dword = 2 bf16 (c even, c odd)
  __shared__ float s_part[2][16][36];
  __shared__ unsigned short p_bf[16][40];
  __shared__ float al_sh[16], l_sh[16];
  const int cnt = (s < 1024) ? (s + 1) : 1024;

  bf16x8 qa[9];
  {
    const unsigned short* qrow = qfull + (size_t)s * 9216 + ln * 576 + half * 288 + quad * 8;
#pragma unroll
    for (int kk = 0; kk < 9; kk++) qa[kk] = *(const bf16x8*)(qrow + kk * 32);
  }
  f32x4 o[8];
#pragma unroll
  for (int i = 0; i < 8; i++) o[i] = (f32x4){0.f, 0.f, 0.f, 0.f};
  float m_run = -3.0e38f, l_run = 0.f;
  const int skey = t >> 3, ssub = t & 7;
  const int scol = skey ^ ((ssub & 3) << 3);           // swizzled staging column
  const int keyi = (kt * 16 + ln) ^ (quad << 3);       // swizzled QK read column
  const int pvoff = (quad ^ ((ln >> 2) & 3)) << 3;     // swizzled PV read base

  // prefetch chunk 0
  float4 pf[9];
  bool vld;
  {
    int gk = skey;
    vld = (gk < cnt);
    if (vld) {
      const unsigned short* sp = kvbf + (size_t)sel[(size_t)s * TOPK_ + gk] * 576;
#pragma unroll
      for (int j = 0; j < 9; j++) pf[j] = *(const float4*)(sp + (ssub + 8 * j) * 8);
    }
  }

  for (int k0 = 0; k0 < cnt; k0 += KC) {
    __syncthreads();  // (1) prev chunk consumers done with kvt2
    if (vld) {
#pragma unroll
      for (int j = 0; j < 9; j++) {
        const unsigned* pv = (const unsigned*)&pf[j];
        int base = ((ssub + 8 * j) * 4) * 36 + scol;
        kvt2[base] = pv[0];
        kvt2[base + 36] = pv[1];
        kvt2[base + 72] = pv[2];
        kvt2[base + 108] = pv[3];
      }
    } else {
#pragma unroll
      for (int j = 0; j < 9; j++) {
        int base = ((ssub + 8 * j) * 4) * 36 + scol;
        kvt2[base] = 0u; kvt2[base + 36] = 0u; kvt2[base + 72] = 0u; kvt2[base + 108] = 0u;
      }
    }
    // T14: issue next chunk's gather now; lands during QK/softmax/PV
    {
      int gkn = k0 + KC + skey;
      bool vn = (gkn < cnt);
      if (vn) {
        const unsigned short* sp = kvbf + (size_t)sel[(size_t)s * TOPK_ + gkn] * 576;
#pragma unroll
        for (int j = 0; j < 9; j++) pf[j] = *(const float4*)(sp + (ssub + 8 * j) * 8);
      }
      vld = vn;
    }
    __syncthreads();  // (2) kvt2 ready
    // QK: wave covers K-half `half`, key-tile kt
    {
      f32x4 sacc = (f32x4){0.f, 0.f, 0.f, 0.f};
#pragma unroll
      for (int kk = 0; kk < 9; kk++) {
        int c2b = half * 144 + kk * 16 + quad * 4;
        unsigned bw[4];
        bw[0] = kvt2[c2b * 36 + keyi];
        bw[1] = kvt2[(c2b + 1) * 36 + keyi];
        bw[2] = kvt2[(c2b + 2) * 36 + keyi];
        bw[3] = kvt2[(c2b + 3) * 36 + keyi];
        sacc = __builtin_amdgcn_mfma_f32_16x16x32_bf16(qa[kk], *(const bf16x8*)bw, sacc, 0, 0, 0);
      }
#pragma unroll
      for (int r = 0; r < 4; r++) s_part[half][quad * 4 + r][kt * 16 + ln] = sacc[r];
    }
    __syncthreads();  // (3) s_part ready
    // in-wave softmax: head h = w*4 + quad (16-lane group), keys (2*ln, 2*ln+1)
    {
      const int h = w * 4 + quad;
      float a0 = s_part[0][h][2 * ln] + s_part[1][h][2 * ln];
      float a1 = s_part[0][h][2 * ln + 1] + s_part[1][h][2 * ln + 1];
      float v0 = (k0 + 2 * ln < cnt) ? a0 : -3.0e38f;
      float v1 = (k0 + 2 * ln + 1 < cnt) ? a1 : -3.0e38f;
      float tm = fmaxf(v0, v1);
      tm = fmaxf(tm, __shfl_xor(tm, 1));
      tm = fmaxf(tm, __shfl_xor(tm, 2));
      tm = fmaxf(tm, __shfl_xor(tm, 4));
      tm = fmaxf(tm, __shfl_xor(tm, 8));
      float mn = fmaxf(m_run, tm);
      float alpha = __expf(m_run - mn);
      m_run = mn;
      float p0 = __expf(v0 - mn);
      float p1 = __expf(v1 - mn);
      unsigned pk = (unsigned)f2bf(p0) | ((unsigned)f2bf(p1) << 16);
      *(unsigned*)&p_bf[h][2 * ln] = pk;
      float rs = p0 + p1;
      rs += __shfl_xor(rs, 1);
      rs += __shfl_xor(rs, 2);
      rs += __shfl_xor(rs, 4);
      rs += __shfl_xor(rs, 8);
      l_run = l_run * alpha + rs;
      if (ln == 0) al_sh[h] = alpha;
    }
    __syncthreads();  // (4) p_bf / al_sh ready
    // PV via MFMA: A = P[h][key], B = V[key][c] from c-pair dwords (swizzled key cols)
    {
      bf16x8 pa = *(const bf16x8*)&p_bf[ln][quad * 8];
      float al0 = al_sh[quad * 4 + 0], al1 = al_sh[quad * 4 + 1];
      float al2 = al_sh[quad * 4 + 2], al3 = al_sh[quad * 4 + 3];
#pragma unroll
      for (int i = 0; i < 8; i++) {
        o[i][0] *= al0; o[i][1] *= al1; o[i][2] *= al2; o[i][3] *= al3;
      }
#pragma unroll
      for (int tau = 0; tau < 4; tau++) {
        const unsigned* kp = &kvt2[(w * 64 + tau * 16 + ln) * 36 + pvoff];
        uint4 lo = *(const uint4*)kp;
        uint4 hi = *(const uint4*)(kp + 4);
        unsigned ev[4], od[4];
        ev[0] = __builtin_amdgcn_perm(lo.y, lo.x, 0x05040100u);
        od[0] = __builtin_amdgcn_perm(lo.y, lo.x, 0x07060302u);
        ev[1] = __builtin_amdgcn_perm(lo.w, lo.z, 0x05040100u);
        od[1] = __builtin_amdgcn_perm(lo.w, lo.z, 0x07060302u);
        ev[2] = __builtin_amdgcn_perm(hi.y, hi.x, 0x05040100u);
        od[2] = __builtin_amdgcn_perm(hi.y, hi.x, 0x07060302u);
        ev[3] = __builtin_amdgcn_perm(hi.w, hi.z, 0x05040100u);
        od[3] = __builtin_amdgcn_perm(hi.w, hi.z, 0x07060302u);
        o[tau * 2]     = __builtin_amdgcn_mfma_f32_16x16x32_bf16(pa, *(const bf16x8*)ev, o[tau * 2], 0, 0, 0);
        o[tau * 2 + 1] = __builtin_amdgcn_mfma_f32_16x16x32_bf16(pa, *(const bf16x8*)od, o[tau * 2 + 1], 0, 0, 0);
      }
    }
  }
  // epilogue: final 1/l per head from owner wave, then write-out
  if (ln == 0) l_sh[w * 4 + quad] = 1.0f / l_run;
  __syncthreads();
  {
    float li[4] = {l_sh[quad * 4 + 0], l_sh[quad * 4 + 1], l_sh[quad * 4 + 2], l_sh[quad * 4 + 3]};
#pragma unroll
    for (int tau = 0; tau < 4; tau++) {
      int c2 = w * 64 + tau * 16 + ln;
#pragma unroll
      for (int r = 0; r < 4; r++) {
        int h = quad * 4 + r;
        unsigned pk = (unsigned)f2bf(o[tau * 2][r] * li[r]) |
                      ((unsigned)f2bf(o[tau * 2 + 1][r] * li[r]) << 16);
        *(unsigned*)(o_c + (size_t)s * 8192 + h * 512 + 2 * c2) = pk;
      }
    }
  }
}

// ---------------- launch ----------------
extern "C" void kernel_launch(void* const* d_in, const int* in_sizes, int n_in,
                              void* d_out, int out_size, void* d_ws, size_t ws_size,
                              hipStream_t stream) {
  const float* hs         = (const float*)d_in[0];
  const float* cosp       = (const float*)d_in[1];
  const float* sinp       = (const float*)d_in[2];
  const float* w_q_a      = (const float*)d_in[3];
  const float* q_a_ln_w   = (const float*)d_in[4];
  const float* w_q_b      = (const float*)d_in[5];
  const float* w_kv_a     = (const float*)d_in[6];
  const float* kv_a_ln_w  = (const float*)d_in[7];
  const float* w_kv_b     = (const float*)d_in[8];
  const float* w_o        = (const float*)d_in[9];
  const float* idx_wq_b   = (const float*)d_in[10];
  const float* idx_wk     = (const float*)d_in[11];
  const float* idx_k_ln_w = (const float*)d_in[12];
  const float* idx_k_ln_b = (const float*)d_in[13];
  const float* idx_w_proj = (const float*)d_in[14];
  float* out = (float*)d_out;

  // ---- compact workspace layout (floats); total 45,320,192 f = 181.3 MB ----
  float* ws = (float*)d_ws;
  float*          qb      = ws;                                   // 6,291,456 f
  float*          cq      = ws + 6291456;                         // 3,145,728 f (dead after rmsnorm)
  unsigned short* qbbf    = (unsigned short*)cq;                  //   alias: 3,145,728 sh
  unsigned short* cqbf    = (unsigned short*)(ws + 9437184);      // 3,145,728 sh
  float*          kvp     = ws + 11010048;                        // 1,310,720 f
  unsigned short* kvbf    = (unsigned short*)(ws + 12320768);     // 1,179,648 sh
  float*          wts     = ws + 12910592;                        // 32,768 f
  int*            sel     = (int*)(ws + 12943360);                // 2,097,152 i
  int*            selcnt  = sel + 2097152;                        // 2,048 i
  float*          ki      = ws + 15042560;                        // 262,144 f
  unsigned short* kibf    = (unsigned short*)(ws + 15304704);     // 262,144 sh
  unsigned short* wkvbbf  = (unsigned short*)(ws + 15435776);     // 2,097,152 sh (512x4096)
  unsigned short* wvT     = (unsigned short*)(ws + 16484352);     // 1,048,576 sh
  unsigned short* attnbbf = (unsigned short*)(ws + 17008640);     // 4,194,304 sh
  unsigned short* o_c     = (unsigned short*)(ws + 19105792);     // 16,777,216 sh
  unsigned short* woT     = o_c;                                  //   alias (o_c dead after wv gemm)
  unsigned short* hsbf    = (unsigned short*)(ws + 27494400);     // 8,388,608 sh
  float*          qi      = ws + 31688704;                        // 4,194,304 f
  unsigned short* qibf    = (unsigned short*)(ws + 35883008);     // 4,194,304 sh
  float*          isc     = ws + 37980160;                        // 4,194,304 f
  unsigned short* qfull   = (unsigned short*)qi;                  //   alias (dead after topk)
  unsigned short* wT      = (unsigned short*)(ws + 42174464);     // 6,291,456 sh transpose scratch

  // 1. casts / cq path (cq: split-K x2 -> 384 blocks; R7 config)
  cast_bf16<<<4096, 256, 0, stream>>>(hs, hsbf);
  transpose_cast<<<dim3(48, 64), 256, 0, stream>>>(w_q_a, wT, 4096, 1536);
  hipMemsetAsync(cq, 0, (size_t)2048 * 1536 * 4, stream);
  gemm_bf16x_sk<<<dim3(12, 16, 2), 256, 0, stream>>>(hsbf, wT, cq, 2048, 4096, 4096, 1536);
  rmsnorm_bf16_kernel<<<2048, 256, 0, stream>>>(cq, q_a_ln_w, cqbf, 1536, 1536);

  // 2. indexer path (qi plain GEMM; ki split-K x8; fused rope+cast kernels)
  transpose_cast<<<dim3(64, 24), 256, 0, stream>>>(idx_wq_b, wT, 1536, 2048);
  gemm_bf16x<<<dim3(16, 16, 1), 256, 0, stream>>>(cqbf, wT, qi, 1536, 1536, 1536, 2048, 0, 0, 0);
  rope_cast_qi<<<2048, 256, 0, stream>>>(qi, cosp, sinp, qibf);
  transpose_cast<<<dim3(4, 64), 256, 0, stream>>>(idx_wk, wT, 4096, 128);
  hipMemsetAsync(ki, 0, (size_t)2048 * 128 * 4, stream);
  gemm_bf16x_sk<<<dim3(1, 16, 8), 256, 0, stream>>>(hsbf, wT, ki, 512, 4096, 4096, 128);
  layernorm_rope_cast<<<2048, 128, 0, stream>>>(ki, idx_k_ln_w, idx_k_ln_b, cosp, sinp, kibf);
  wts_kernel<<<2048, 256, 0, stream>>>(hs, idx_w_proj, wts);
  indexer_mfma<<<528, 256, 0, stream>>>(qibf, kibf, wts, isc);
  topk_select<<<2048, 256, 0, stream>>>(isc, sel, selcnt);

  // 3. q path (fused rope+cast+qfull-rope; qfull aliases qi, dead after topk)
  transpose_cast<<<dim3(96, 24), 256, 0, stream>>>(w_q_b, wT, 1536, 3072);
  gemm_bf16x<<<dim3(24, 16, 1), 256, 0, stream>>>(cqbf, wT, qb, 1536, 1536, 1536, 3072, 0, 0, 0);
  rope_cast_q<<<2048, 256, 0, stream>>>(qb, cosp, sinp, qbbf, qfull);

  // 4. kv path (padded N=640; split-K x4 -> 320 blocks; R7 config)
  transpose_cast<<<dim3(20, 64), 256, 0, stream>>>(w_kv_a, wT, 4096, 576);
  hipMemsetAsync(kvp, 0, (size_t)2048 * 640 * 4, stream);
  gemm_bf16x_sk<<<dim3(5, 16, 4), 256, 0, stream>>>(hsbf, wT, kvp, 1024, 4096, 4096, 640);
  rmsnorm_kernel<<<2048, 256, 0, stream>>>(kvp, kv_a_ln_w, 512, 640);
  rope_k_inter<<<256, 256, 0, stream>>>(kvp, cosp, sinp, 640);
  kv_to_bf16_pad<<<2048, 256, 0, stream>>>(kvp, kvbf);

  // 5. absorbed q: qfull[s][h*576 + 0..511] = (q_nope @ w_k[h]^T)*qscale (rope section already filled)
  cast_bf16<<<1024, 256, 0, stream>>>(w_kv_b, wkvbbf);
  gemm_bf16x_bf<<<dim3(4, 16, 16), 256, 0, stream>>>(qbbf, wkvbbf, qfull,
                                                     128, 3072, 4096, 9216, 192, 256, 576,
                                                     0.07216878364870322f);

  // 6. flash attention
  flash_attn2<<<2048, 256, 0, stream>>>(qfull, kvbf, sel, o_c);

  // 7. attn_out[s][h*128+d] = o_c[s][h*512+:] @ w_v[h]
  transpose_wv<<<dim3(4, 16), 256, 0, stream>>>(wkvbbf, wvT);
  gemm_bf16x_bf<<<dim3(1, 16, 16), 256, 0, stream>>>(o_c, wvT, attnbbf,
                                                     512, 8192, 512, 2048, 512, 65536, 128, 1.0f);

  // 8. out = attn_out @ w_o (plain GEMM, R7 config)
  transpose_cast<<<dim3(128, 32), 256, 0, stream>>>(w_o, woT, 2048, 4096);
  gemm_bf16x<<<dim3(32, 16, 1), 256, 0, stream>>>(attnbbf, woT, out, 2048, 2048, 2048, 4096, 0, 0, 0);
}